// Round 5
// baseline (135.038 us; speedup 1.0000x reference)
//
#include <hip/hip_runtime.h>

#define B 2
#define S 2048
#define A 16
#define H 1024
#define NH 16
#define HD 64
#define KT 16  // k-rows per scores block
#define HG 8   // heads per scores block (32 KB LDS)
#define CH 4   // j-chunks per head in kQW
#define QC 16  // query rows per kSD block

// ---- kQW: fused masked-mean + Q projection + effective K-weights ----------
// grid = B*NH*CH = 128 blocks. Each block redundantly computes agg[b] and
// q[b,h,:] (cheap, L2-hot), then 256 weff outputs with coalesced Wk reads.
__global__ __launch_bounds__(256) void kQW(const float* __restrict__ h2,
                                           const int* __restrict__ amask,
                                           const float* __restrict__ Wq,
                                           const float* __restrict__ Wk,
                                           float* __restrict__ weff) {
    __shared__ float agg[H];
    __shared__ float qs[HD];
    int blk = blockIdx.x;
    int c = blk & (CH - 1);
    int bh = blk / CH;
    int b = bh >> 4, h = bh & 15;
    int tid = threadIdx.x;

    // masked mean over aspects: thread owns 4 contiguous columns
    {
        const float4* h2b = (const float4*)(h2 + (size_t)b * A * H);
        float4 sum = make_float4(0.f, 0.f, 0.f, 0.f);
        int cnt = 0;
#pragma unroll
        for (int a = 0; a < A; a++) {
            if (amask[b * A + a]) {
                float4 v = h2b[a * (H / 4) + tid];
                sum.x += v.x; sum.y += v.y; sum.z += v.z; sum.w += v.w; cnt++;
            }
        }
        float inv = 1.0f / (float)(cnt > 0 ? cnt : 1);
        ((float4*)agg)[tid] = make_float4(sum.x * inv, sum.y * inv, sum.z * inv, sum.w * inv);
    }
    __syncthreads();

    // q for this head: 64 wave-dots (4 waves x 16)
    int wave = tid >> 6, lane = tid & 63;
    const float4* ag = (const float4*)agg;
    for (int d = wave * 16; d < wave * 16 + 16; d++) {
        const float4* wr = (const float4*)(Wq + (size_t)(h * HD + d) * H);
        float acc = 0.f;
#pragma unroll
        for (int t = 0; t < 4; t++) {
            int j4 = lane + 64 * t;
            float4 a4 = ag[j4], w4 = wr[j4];
            acc += a4.x * w4.x + a4.y * w4.y + a4.z * w4.z + a4.w * w4.w;
        }
        for (int off = 32; off > 0; off >>= 1) acc += __shfl_down(acc, off);
        if (lane == 0) qs[d] = acc;
    }
    __syncthreads();

    // weff chunk: one thread per output column j; Wk reads coalesced
    int j = c * 256 + tid;
    float acc = 0.f;
#pragma unroll 8
    for (int d = 0; d < HD; d++) acc += qs[d] * Wk[(size_t)(h * HD + d) * H + j];
    weff[((size_t)b * NH + h) * H + j] = acc * 0.125f;  // scale = 64^-0.5
}

// ---- kB: scores s[b,h,k] = weff[b,h,:] . h1[b,k,:] ------------------------
// grid = B * (S/KT) * 2 head-groups = 512 blocks; 32 KB LDS
__global__ __launch_bounds__(256) void kB(const float* __restrict__ h1,
                                          const float* __restrict__ weff,
                                          float* __restrict__ s) {
    __shared__ float4 lw[HG * H / 4];  // 32 KB
    int blk = blockIdx.x;
    int hg = blk & 1;
    int rest = blk >> 1;
    int kt = rest % (S / KT);
    int b  = rest / (S / KT);
    const float4* wsrc = (const float4*)(weff + ((size_t)b * NH + hg * HG) * H);
    for (int i = threadIdx.x; i < HG * H / 4; i += 256) lw[i] = wsrc[i];
    __syncthreads();

    int wave = threadIdx.x >> 6, lane = threadIdx.x & 63;
    for (int kl = wave; kl < KT; kl += 4) {
        int k = kt * KT + kl;
        const float4* row = (const float4*)(h1 + ((size_t)b * S + k) * H);
        float4 x[4];
#pragma unroll
        for (int t = 0; t < 4; t++) x[t] = row[lane + 64 * t];
#pragma unroll
        for (int hh = 0; hh < HG; hh++) {
            float acc = 0.f;
#pragma unroll
            for (int t = 0; t < 4; t++) {
                float4 wv = lw[hh * (H / 4) + lane + 64 * t];
                acc += wv.x * x[t].x + wv.y * x[t].y + wv.z * x[t].z + wv.w * x[t].w;
            }
            for (int off = 32; off > 0; off >>= 1) acc += __shfl_down(acc, off);
            if (lane == 0) s[((size_t)b * NH + hg * HG + hh) * S + k] = acc;
        }
    }
}

// ---- kSD: fused masked softmax stats + head-mean weight + broadcast -------
// grid = B * (S/QC) = 256 blocks. Each block redundantly computes the batch
// stats (s[b] is 128 KB, L2-hot), then its full 2048-wide w row into LDS,
// then streams QC=16 identical output rows.
__global__ __launch_bounds__(256) void kSD(const float* __restrict__ s,
                                           const int* __restrict__ smask,
                                           float* __restrict__ out) {
    __shared__ float mh[NH], ih[NH];
    __shared__ int   mk[S];     // 8 KB
    __shared__ float wch[S];    // 8 KB
    int blk = blockIdx.x;
    int b  = blk >> 7;                  // 128 blocks per batch
    int q0 = (blk & 127) * QC;
    int tid = threadIdx.x, wave = tid >> 6, lane = tid & 63;

    // preload mask row into LDS
    {
        const int4* msrc = (const int4*)(smask + b * S);
#pragma unroll
        for (int t = 0; t < 2; t++) ((int4*)mk)[tid + 256 * t] = msrc[tid + 256 * t];
    }
    __syncthreads();

    // stats: wave w owns heads 4w..4w+3 (two passes: max, then exp-sum)
#pragma unroll
    for (int hh = 0; hh < 4; hh++) {
        int h = wave * 4 + hh;
        const float4* srow = (const float4*)(s + ((size_t)b * NH + h) * S);
        float mx = -3.4e38f;
#pragma unroll
        for (int t = 0; t < 8; t++) {
            int i = lane + 64 * t;
            float4 v = srow[i]; int4 mm = ((const int4*)mk)[i];
            if (mm.x) mx = fmaxf(mx, v.x);
            if (mm.y) mx = fmaxf(mx, v.y);
            if (mm.z) mx = fmaxf(mx, v.z);
            if (mm.w) mx = fmaxf(mx, v.w);
        }
        for (int off = 32; off > 0; off >>= 1) mx = fmaxf(mx, __shfl_down(mx, off));
        mx = __shfl(mx, 0);
        float sum = 0.f;
#pragma unroll
        for (int t = 0; t < 8; t++) {
            int i = lane + 64 * t;
            float4 v = srow[i]; int4 mm = ((const int4*)mk)[i];
            if (mm.x) sum += expf(v.x - mx);
            if (mm.y) sum += expf(v.y - mx);
            if (mm.z) sum += expf(v.z - mx);
            if (mm.w) sum += expf(v.w - mx);
        }
        for (int off = 32; off > 0; off >>= 1) sum += __shfl_down(sum, off);
        if (lane == 0) { mh[h] = mx; ih[h] = 1.0f / sum; }
    }
    __syncthreads();

    // w row: 2 float4 per thread
    float lm[NH], li[NH];
#pragma unroll
    for (int h = 0; h < NH; h++) { lm[h] = mh[h]; li[h] = ih[h]; }
#pragma unroll
    for (int t = 0; t < 2; t++) {
        int i = tid + 256 * t;
        int4 mm = ((const int4*)mk)[i];
        float4 val = make_float4(0.f, 0.f, 0.f, 0.f);
#pragma unroll
        for (int h = 0; h < NH; h++) {
            float4 sv = ((const float4*)(s + ((size_t)b * NH + h) * S))[i];
            val.x += expf(sv.x - lm[h]) * li[h];
            val.y += expf(sv.y - lm[h]) * li[h];
            val.z += expf(sv.z - lm[h]) * li[h];
            val.w += expf(sv.w - lm[h]) * li[h];
        }
        const float inh = 1.0f / NH;
        val.x = mm.x ? val.x * inh : 0.f;
        val.y = mm.y ? val.y * inh : 0.f;
        val.z = mm.z ? val.z * inh : 0.f;
        val.w = mm.w ? val.w * inh : 0.f;
        ((float4*)wch)[i] = val;
    }
    __syncthreads();

    // broadcast QC rows
    float4 v0 = ((float4*)wch)[tid];
    float4 v1 = ((float4*)wch)[tid + 256];
#pragma unroll
    for (int qi = 0; qi < QC; qi++) {
        float4* dst = (float4*)(out + ((size_t)(b * S + q0 + qi)) * S);
        dst[tid] = v0;
        dst[tid + 256] = v1;
    }
}

extern "C" void kernel_launch(void* const* d_in, const int* in_sizes, int n_in,
                              void* d_out, int out_size, void* d_ws, size_t ws_size,
                              hipStream_t stream) {
    const float* h1    = (const float*)d_in[0];   // [B,S,H]
    const float* h2    = (const float*)d_in[1];   // [B,A,H]
    const int*   smask = (const int*)d_in[2];     // [B,S]
    const int*   amask = (const int*)d_in[3];     // [B,A]
    const float* Wq    = (const float*)d_in[4];   // [H,H]
    const float* Wk    = (const float*)d_in[5];   // [H,H]
    float* out = (float*)d_out;                   // [B,S,S]
    float* ws  = (float*)d_ws;

    float* weff = ws;            // B*NH*H = 32768 floats
    float* s    = ws + 32768;    // B*NH*S = 65536 floats

    kQW<<<B * NH * CH, 256, 0, stream>>>(h2, amask, Wq, Wk, weff);
    kB <<<B * (S / KT) * 2, 256, 0, stream>>>(h1, weff, s);
    kSD<<<B * (S / QC), 256, 0, stream>>>(s, smask, out);
}